// Round 3
// baseline (14860.362 us; speedup 1.0000x reference)
//
#include <hip/hip_runtime.h>
#include <hip/hip_bf16.h>

#define SEQ    4096
#define HIDDEN 256
#define G3     768   // 3*HIDDEN
// xg layout: [t][blk(2)][tid(512)][pair(3)][16B] ; slab = 2*512*48 = 49152 B/t
#define SLAB   49152

typedef __attribute__((ext_vector_type(8))) short bf16x8;
typedef __attribute__((ext_vector_type(4))) float f32x4;

__device__ __forceinline__ unsigned int pkbf(float a, float b) {
    __hip_bfloat162 h = __float22bfloat162_rn(make_float2(a, b));
    union { __hip_bfloat162 h2; unsigned int u; } c; c.h2 = h; return c.u;
}
__device__ __forceinline__ unsigned short f2bf(float a) {
    __hip_bfloat16 h = __float2bfloat16(a);
    union { __hip_bfloat16 h1; unsigned short u; } c; c.h1 = h; return c.u;
}
__device__ __forceinline__ float bflo(unsigned int q) { return __uint_as_float(q << 16); }
__device__ __forceinline__ float bfhi(unsigned int q) { return __uint_as_float(q & 0xFFFF0000u); }

// ---------------------------------------------------------------------------
// Kernel B: x_proj = x @ W_ih^T (scaled, bias-folded), bf16.
// Writes xg in the scan's per-consumer-thread packed layout (48 B per thread
// per t, pairs r/z/n at +0/+16/+32).
// ---------------------------------------------------------------------------
__global__ __launch_bounds__(512, 2) void gru_xproj(
    const float* __restrict__ x, const float* __restrict__ w_ih,
    const float* __restrict__ b_ih, const float* __restrict__ b_hh,
    char* __restrict__ xg)
{
    __shared__ __align__(16) char alds[2][16384];   // [2 buf][32 rows][512 B], XOR-swizzled
    const int tid = threadIdx.x;
    const int lane = tid & 63, wave = tid >> 6;
    const int l15 = lane & 15, l4 = lane >> 4;
    const int t0 = blockIdx.x * 32;
    const int gbase = blockIdx.y * 384 + wave * 48;

    bf16x8 wf[3][8];
    float bias[3];
    #pragma unroll
    for (int n = 0; n < 3; ++n) {
        const int g = gbase + n * 16 + l15;
        const float s = (g < 256) ? -1.442695041f : ((g < 512) ? 1.442695041f : 2.885390082f);
        bias[n] = (g < 512) ? s * (b_ih[g] + b_hh[g]) : s * b_ih[g];
        #pragma unroll
        for (int kk = 0; kk < 8; ++kk) {
            const float* p = w_ih + g * 256 + kk * 32 + l4 * 8;
            float4 aa = *(const float4*)(p);
            float4 bb = *(const float4*)(p + 4);
            union { bf16x8 v; unsigned int u[4]; } f;
            f.u[0] = pkbf(s * aa.x, s * aa.y); f.u[1] = pkbf(s * aa.z, s * aa.w);
            f.u[2] = pkbf(s * bb.x, s * bb.y); f.u[3] = pkbf(s * bb.z, s * bb.w);
            wf[n][kk] = f.v;
        }
    }

    for (int tt = 0; tt < 32; ++tt) {
        const int t = t0 + tt;
        const int buf = tt & 1;
        {
            const int row = tid >> 4;           // batch 0..31
            const int k0  = (tid & 15) * 16;    // 16 floats each
            const float* xp = x + ((size_t)row * SEQ + t) * 256 + k0;
            float4 u0 = *(const float4*)(xp + 0);
            float4 u1 = *(const float4*)(xp + 4);
            float4 u2 = *(const float4*)(xp + 8);
            float4 u3 = *(const float4*)(xp + 12);
            union { bf16x8 v; unsigned int u[4]; } w0, w1;
            w0.u[0] = pkbf(u0.x,u0.y); w0.u[1] = pkbf(u0.z,u0.w);
            w0.u[2] = pkbf(u1.x,u1.y); w0.u[3] = pkbf(u1.z,u1.w);
            w1.u[0] = pkbf(u2.x,u2.y); w1.u[1] = pkbf(u2.z,u2.w);
            w1.u[2] = pkbf(u3.x,u3.y); w1.u[3] = pkbf(u3.z,u3.w);
            const int base = row * 512 + k0 * 2;
            const int swz  = (row & 7) << 4;
            *(bf16x8*)(alds[buf] + ((base     ) ^ swz)) = w0.v;
            *(bf16x8*)(alds[buf] + ((base + 16) ^ swz)) = w1.v;
        }
        __syncthreads();

        f32x4 acc[2][3];
        #pragma unroll
        for (int m = 0; m < 2; ++m)
            #pragma unroll
            for (int n = 0; n < 3; ++n) acc[m][n] = (f32x4){0.f,0.f,0.f,0.f};

        #pragma unroll
        for (int kk = 0; kk < 8; ++kk) {
            const int sw = (l15 & 7) << 4;
            bf16x8 a0 = *(const bf16x8*)(alds[buf] + (((l15     ) * 512 + kk * 64 + l4 * 16) ^ sw));
            bf16x8 a1 = *(const bf16x8*)(alds[buf] + (((l15 + 16) * 512 + kk * 64 + l4 * 16) ^ sw));
            #pragma unroll
            for (int n = 0; n < 3; ++n) {
                acc[0][n] = __builtin_amdgcn_mfma_f32_16x16x32_bf16(a0, wf[n][kk], acc[0][n], 0, 0, 0);
                acc[1][n] = __builtin_amdgcn_mfma_f32_16x16x32_bf16(a1, wf[n][kk], acc[1][n], 0, 0, 0);
            }
        }
        // store into consumer-packed layout
        #pragma unroll
        for (int m = 0; m < 2; ++m)
            #pragma unroll
            for (int n = 0; n < 3; ++n) {
                const int g = gbase + n * 16 + l15;
                uint2 q;
                q.x = pkbf(acc[m][n][0] + bias[n], acc[m][n][1] + bias[n]);
                q.y = pkbf(acc[m][n][2] + bias[n], acc[m][n][3] + bias[n]);
                const int p = g >> 8;                 // gate/pair index
                const int g255 = g & 255;
                const int wavec = g255 >> 5;          // consumer wave
                const int w = (g255 >> 4) & 1;        // consumer jt word
                const int tidc = wavec * 64 + l4 * 16 + (g & 15);
                *(uint2*)(xg + (size_t)t * SLAB + m * 24576 + tidc * 48 + p * 16 + w * 8) = q;
            }
    }
}

// ---------------------------------------------------------------------------
// Kernel C: persistent GRU scan. grid(2): block b owns batches [16b,16b+16).
// 8 waves; wave owns hidden cols [32w,32w+32) x 3 gates = 6 N-tiles, all
// weights in the unified VGPR/AGPR file. h double-buffered bf16 in LDS.
// Raw s_barrier + lgkmcnt(0) only; xg prefetch & out stores stay in flight.
// ---------------------------------------------------------------------------
__global__ __launch_bounds__(512, 2) void gru_rec(
    const float* __restrict__ w_hh, const float* __restrict__ b_hh,
    const float* __restrict__ h0, const char* __restrict__ xg,
    float* __restrict__ out)
{
    __shared__ __align__(16) char hb[2][8192];
    const int tid = threadIdx.x, lane = tid & 63, wave = tid >> 6;
    const int l15 = lane & 15, l4 = lane >> 4;
    const int blk = blockIdx.x;
    const int j0 = wave * 32;

    // 6 weight tiles (r,z,n x jt0,jt1), scaled, in the unified reg file: 192
    bf16x8 wf[6][8];
    #pragma unroll
    for (int g6 = 0; g6 < 6; ++g6) {
        const int gate = g6 >> 1, jt = g6 & 1;
        const int row = gate * 256 + j0 + jt * 16 + l15;
        const float s = (gate == 0) ? -1.442695041f : ((gate == 1) ? 1.442695041f : 2.885390082f);
        #pragma unroll
        for (int kk = 0; kk < 8; ++kk) {
            const float* p = w_hh + row * 256 + kk * 32 + l4 * 8;
            float4 aa = *(const float4*)p;
            float4 bb = *(const float4*)(p + 4);
            union { bf16x8 v; unsigned int u[4]; } f;
            f.u[0] = pkbf(s * aa.x, s * aa.y); f.u[1] = pkbf(s * aa.z, s * aa.w);
            f.u[2] = pkbf(s * bb.x, s * bb.y); f.u[3] = pkbf(s * bb.z, s * bb.w);
            wf[g6][kk] = f.v;
        }
    }
    float bHn[2];
    bHn[0] = 2.885390082f * b_hh[512 + j0 + l15];
    bHn[1] = 2.885390082f * b_hh[512 + j0 + 16 + l15];

    // initial h: fp32 in regs + bf16 into hb buffer 0
    float hprev[2][4];
    #pragma unroll
    for (int jt = 0; jt < 2; ++jt)
        #pragma unroll
        for (int i = 0; i < 4; ++i) {
            const int b = blk * 16 + l4 * 4 + i;
            const int j = j0 + jt * 16 + l15;
            float h = h0[b * 256 + j];
            hprev[jt][i] = h;
            const int row = l4 * 4 + i;
            *(unsigned short*)(&hb[0][0] + ((row * 512 + j * 2) ^ ((row & 7) << 4))) = f2bf(h);
        }

    const char* xqb = xg + blk * 24576 + tid * 48;
    char* ob = (char*)out + ((size_t)(blk * 16 + l4 * 4) * SEQ * 256 + j0 + l15) * 4;

    uint4 xq0 = *(const uint4*)(xqb + 0);
    uint4 xq1 = *(const uint4*)(xqb + 16);
    uint4 xq2 = *(const uint4*)(xqb + 32);
    xqb += SLAB;

    __builtin_amdgcn_sched_barrier(0);
    asm volatile("s_waitcnt lgkmcnt(0)" ::: "memory");
    __builtin_amdgcn_s_barrier();
    __builtin_amdgcn_sched_barrier(0);

#define GATES(P_, JT_, AR, AZ, AN, QX, QY) do { \
    float xn[4] = { bflo(QX), bfhi(QX), bflo(QY), bfhi(QY) }; \
    _Pragma("unroll") for (int i = 0; i < 4; ++i) { \
        float r   = __builtin_amdgcn_rcpf(1.0f + __builtin_amdgcn_exp2f(AR[i])); \
        float uu  = __builtin_amdgcn_rcpf(1.0f + __builtin_amdgcn_exp2f(AZ[i])); \
        float pre = fmaf(r, AN[i], xn[i]); \
        float nn  = fmaf(-2.0f, __builtin_amdgcn_rcpf(1.0f + __builtin_amdgcn_exp2f(pre)), 1.0f); \
        float hp  = hprev[JT_][i]; \
        float hnv = fmaf(uu, nn - hp, hp); \
        hprev[JT_][i] = hnv; \
        const int row_ = l4 * 4 + i; \
        *(unsigned short*)(&hb[1 - (P_)][0] + \
            ((row_ * 512 + (j0 + (JT_) * 16 + l15) * 2) ^ ((row_ & 7) << 4))) = f2bf(hnv); \
        *(float*)(ob + (size_t)i * (SEQ * 1024) + (JT_) * 64) = hnv; \
    } } while (0)

#define BODY(T_, P_) do { \
    f32x4 acc0 = { bflo(xq0.x), bfhi(xq0.x), bflo(xq0.y), bfhi(xq0.y) }; \
    f32x4 acc1 = { bflo(xq0.z), bfhi(xq0.z), bflo(xq0.w), bfhi(xq0.w) }; \
    f32x4 acc2 = { bflo(xq1.x), bfhi(xq1.x), bflo(xq1.y), bfhi(xq1.y) }; \
    f32x4 acc3 = { bflo(xq1.z), bfhi(xq1.z), bflo(xq1.w), bfhi(xq1.w) }; \
    f32x4 acc4 = { bHn[0], bHn[0], bHn[0], bHn[0] }; \
    f32x4 acc5 = { bHn[1], bHn[1], bHn[1], bHn[1] }; \
    xq0 = *(const uint4*)(xqb + 0); \
    xq1 = *(const uint4*)(xqb + 16); \
    _Pragma("unroll") for (int kk = 0; kk < 8; ++kk) { \
        bf16x8 a_ = *(const bf16x8*)(&hb[P_][0] + \
                        ((l15 * 512 + kk * 64 + l4 * 16) ^ ((l15 & 7) << 4))); \
        acc0 = __builtin_amdgcn_mfma_f32_16x16x32_bf16(a_, wf[0][kk], acc0, 0, 0, 0); \
        acc1 = __builtin_amdgcn_mfma_f32_16x16x32_bf16(a_, wf[1][kk], acc1, 0, 0, 0); \
        acc2 = __builtin_amdgcn_mfma_f32_16x16x32_bf16(a_, wf[2][kk], acc2, 0, 0, 0); \
        acc3 = __builtin_amdgcn_mfma_f32_16x16x32_bf16(a_, wf[3][kk], acc3, 0, 0, 0); \
        acc4 = __builtin_amdgcn_mfma_f32_16x16x32_bf16(a_, wf[4][kk], acc4, 0, 0, 0); \
        acc5 = __builtin_amdgcn_mfma_f32_16x16x32_bf16(a_, wf[5][kk], acc5, 0, 0, 0); \
    } \
    GATES(P_, 0, acc0, acc2, acc4, xq2.x, xq2.y); \
    GATES(P_, 1, acc1, acc3, acc5, xq2.z, xq2.w); \
    xq2 = *(const uint4*)(xqb + 32); \
    if ((T_) + 2 < SEQ) xqb += SLAB; \
    ob += 1024; \
    __builtin_amdgcn_sched_barrier(0); \
    asm volatile("s_waitcnt lgkmcnt(0)" ::: "memory"); \
    __builtin_amdgcn_s_barrier(); \
    __builtin_amdgcn_sched_barrier(0); \
} while (0)

    for (int tt = 0; tt < SEQ; tt += 2) {
        BODY(tt + 0, 0);
        BODY(tt + 1, 1);
    }
#undef BODY
#undef GATES
}

extern "C" void kernel_launch(void* const* d_in, const int* in_sizes, int n_in,
                              void* d_out, int out_size, void* d_ws, size_t ws_size,
                              hipStream_t stream) {
    const float* x    = (const float*)d_in[0];
    const float* h0   = (const float*)d_in[1];
    const float* w_ih = (const float*)d_in[2];
    const float* w_hh = (const float*)d_in[3];
    const float* b_ih = (const float*)d_in[4];
    const float* b_hh = (const float*)d_in[5];
    float* out = (float*)d_out;
    char* xg = (char*)d_ws;   // needs SEQ*49152 = 192 MB

    (void)in_sizes; (void)n_in; (void)out_size; (void)ws_size;

    gru_xproj<<<dim3(SEQ / 32, 2), dim3(512), 0, stream>>>(x, w_ih, b_ih, b_hh, xg);
    gru_rec<<<dim3(2), dim3(512), 0, stream>>>(w_hh, b_hh, h0, xg, out);
}

// Round 4
// 9613.132 us; speedup vs baseline: 1.5458x; 1.5458x over previous
//
#include <hip/hip_runtime.h>
#include <hip/hip_bf16.h>

#define SEQ    4096
#define HIDDEN 256
#define G3     768   // 3*HIDDEN
// xg layout: [t][blk(2)][tid(512)][pair(3)][16B] ; slab = 2*512*48 = 49152 B/t
#define SLAB   49152

typedef __attribute__((ext_vector_type(8))) short bf16x8;
typedef __attribute__((ext_vector_type(4))) float f32x4;

__device__ __forceinline__ unsigned int pkbf(float a, float b) {
    __hip_bfloat162 h = __float22bfloat162_rn(make_float2(a, b));
    union { __hip_bfloat162 h2; unsigned int u; } c; c.h2 = h; return c.u;
}
__device__ __forceinline__ unsigned short f2bf(float a) {
    __hip_bfloat16 h = __float2bfloat16(a);
    union { __hip_bfloat16 h1; unsigned short u; } c; c.h1 = h; return c.u;
}
__device__ __forceinline__ float bflo(unsigned int q) { return __uint_as_float(q << 16); }
__device__ __forceinline__ float bfhi(unsigned int q) { return __uint_as_float(q & 0xFFFF0000u); }

// ---------------------------------------------------------------------------
// Kernel B: x_proj = x @ W_ih^T (scaled, bias-folded), bf16.
// Writes xg in the scan's per-consumer-thread packed layout (48 B per thread
// per t, pairs r/z/n at +0/+16/+32). Unchanged from round 3 (passes).
// ---------------------------------------------------------------------------
__global__ __launch_bounds__(512, 2) void gru_xproj(
    const float* __restrict__ x, const float* __restrict__ w_ih,
    const float* __restrict__ b_ih, const float* __restrict__ b_hh,
    char* __restrict__ xg)
{
    __shared__ __align__(16) char alds[2][16384];   // [2 buf][32 rows][512 B], XOR-swizzled
    const int tid = threadIdx.x;
    const int lane = tid & 63, wave = tid >> 6;
    const int l15 = lane & 15, l4 = lane >> 4;
    const int t0 = blockIdx.x * 32;
    const int gbase = blockIdx.y * 384 + wave * 48;

    bf16x8 wf[3][8];
    float bias[3];
    #pragma unroll
    for (int n = 0; n < 3; ++n) {
        const int g = gbase + n * 16 + l15;
        const float s = (g < 256) ? -1.442695041f : ((g < 512) ? 1.442695041f : 2.885390082f);
        bias[n] = (g < 512) ? s * (b_ih[g] + b_hh[g]) : s * b_ih[g];
        #pragma unroll
        for (int kk = 0; kk < 8; ++kk) {
            const float* p = w_ih + g * 256 + kk * 32 + l4 * 8;
            float4 aa = *(const float4*)(p);
            float4 bb = *(const float4*)(p + 4);
            union { bf16x8 v; unsigned int u[4]; } f;
            f.u[0] = pkbf(s * aa.x, s * aa.y); f.u[1] = pkbf(s * aa.z, s * aa.w);
            f.u[2] = pkbf(s * bb.x, s * bb.y); f.u[3] = pkbf(s * bb.z, s * bb.w);
            wf[n][kk] = f.v;
        }
    }

    for (int tt = 0; tt < 32; ++tt) {
        const int t = t0 + tt;
        const int buf = tt & 1;
        {
            const int row = tid >> 4;           // batch 0..31
            const int k0  = (tid & 15) * 16;    // 16 floats each
            const float* xp = x + ((size_t)row * SEQ + t) * 256 + k0;
            float4 u0 = *(const float4*)(xp + 0);
            float4 u1 = *(const float4*)(xp + 4);
            float4 u2 = *(const float4*)(xp + 8);
            float4 u3 = *(const float4*)(xp + 12);
            union { bf16x8 v; unsigned int u[4]; } w0, w1;
            w0.u[0] = pkbf(u0.x,u0.y); w0.u[1] = pkbf(u0.z,u0.w);
            w0.u[2] = pkbf(u1.x,u1.y); w0.u[3] = pkbf(u1.z,u1.w);
            w1.u[0] = pkbf(u2.x,u2.y); w1.u[1] = pkbf(u2.z,u2.w);
            w1.u[2] = pkbf(u3.x,u3.y); w1.u[3] = pkbf(u3.z,u3.w);
            const int base = row * 512 + k0 * 2;
            const int swz  = (row & 7) << 4;
            *(bf16x8*)(alds[buf] + ((base     ) ^ swz)) = w0.v;
            *(bf16x8*)(alds[buf] + ((base + 16) ^ swz)) = w1.v;
        }
        __syncthreads();

        f32x4 acc[2][3];
        #pragma unroll
        for (int m = 0; m < 2; ++m)
            #pragma unroll
            for (int n = 0; n < 3; ++n) acc[m][n] = (f32x4){0.f,0.f,0.f,0.f};

        #pragma unroll
        for (int kk = 0; kk < 8; ++kk) {
            const int sw = (l15 & 7) << 4;
            bf16x8 a0 = *(const bf16x8*)(alds[buf] + (((l15     ) * 512 + kk * 64 + l4 * 16) ^ sw));
            bf16x8 a1 = *(const bf16x8*)(alds[buf] + (((l15 + 16) * 512 + kk * 64 + l4 * 16) ^ sw));
            #pragma unroll
            for (int n = 0; n < 3; ++n) {
                acc[0][n] = __builtin_amdgcn_mfma_f32_16x16x32_bf16(a0, wf[n][kk], acc[0][n], 0, 0, 0);
                acc[1][n] = __builtin_amdgcn_mfma_f32_16x16x32_bf16(a1, wf[n][kk], acc[1][n], 0, 0, 0);
            }
        }
        #pragma unroll
        for (int m = 0; m < 2; ++m)
            #pragma unroll
            for (int n = 0; n < 3; ++n) {
                const int g = gbase + n * 16 + l15;
                uint2 q;
                q.x = pkbf(acc[m][n][0] + bias[n], acc[m][n][1] + bias[n]);
                q.y = pkbf(acc[m][n][2] + bias[n], acc[m][n][3] + bias[n]);
                const int p = g >> 8;                 // gate/pair index
                const int g255 = g & 255;
                const int wavec = g255 >> 5;          // consumer wave
                const int w = (g255 >> 4) & 1;        // consumer jt word
                const int tidc = wavec * 64 + l4 * 16 + (g & 15);
                *(uint2*)(xg + (size_t)t * SLAB + m * 24576 + tidc * 48 + p * 16 + w * 8) = q;
            }
    }
}

// ---------------------------------------------------------------------------
// Kernel C: persistent GRU scan. grid(2): block b owns batches [16b,16b+16).
// 8 waves; wave owns hidden cols [32w,32w+32) x 3 gates = 6 N-tiles, all
// weights in the unified VGPR/AGPR file.
// h double-buffered bf16 in LDS, K-SLICED layout: [buf][kk(8)][row(16)][32 bf16].
//   read  addr = l15*64 + l4*16            (+ kk*1024 + P*8192 in offset field)
//   write addr = wave*1024 + l4*256 + l15*2 (+ i*64 + jt*32 + P*8192 in offset)
// -> zero per-step LDS address VALU, conflict-free reads, no swizzle.
// ---------------------------------------------------------------------------
__global__ __launch_bounds__(512, 2) void gru_rec(
    const float* __restrict__ w_hh, const float* __restrict__ b_hh,
    const float* __restrict__ h0, const char* __restrict__ xg,
    float* __restrict__ out)
{
    __shared__ __align__(16) char hb[2][8192];
    const int tid = threadIdx.x, lane = tid & 63, wave = tid >> 6;
    const int l15 = lane & 15, l4 = lane >> 4;
    const int blk = blockIdx.x;
    const int j0 = wave * 32;

    // 6 weight tiles (r,z,n x jt0,jt1), scaled, in the unified reg file: 192
    bf16x8 wf[6][8];
    #pragma unroll
    for (int g6 = 0; g6 < 6; ++g6) {
        const int gate = g6 >> 1, jt = g6 & 1;
        const int row = gate * 256 + j0 + jt * 16 + l15;
        const float s = (gate == 0) ? -1.442695041f : ((gate == 1) ? 1.442695041f : 2.885390082f);
        #pragma unroll
        for (int kk = 0; kk < 8; ++kk) {
            const float* p = w_hh + row * 256 + kk * 32 + l4 * 8;
            float4 aa = *(const float4*)p;
            float4 bb = *(const float4*)(p + 4);
            union { bf16x8 v; unsigned int u[4]; } f;
            f.u[0] = pkbf(s * aa.x, s * aa.y); f.u[1] = pkbf(s * aa.z, s * aa.w);
            f.u[2] = pkbf(s * bb.x, s * bb.y); f.u[3] = pkbf(s * bb.z, s * bb.w);
            wf[g6][kk] = f.v;
        }
    }
    float bHn[2];
    bHn[0] = 2.885390082f * b_hh[512 + j0 + l15];
    bHn[1] = 2.885390082f * b_hh[512 + j0 + 16 + l15];

    // LDS base pointers (all per-step offsets are compile-time immediates)
    char* hwp = &hb[0][0] + (wave * 1024 + l4 * 256 + l15 * 2);
    const char* hrp = &hb[0][0] + (l15 * 64 + l4 * 16);

    // initial h: fp32 in regs + bf16 into hb buffer 0 (K-sliced layout)
    float hprev[2][4];
    #pragma unroll
    for (int jt = 0; jt < 2; ++jt)
        #pragma unroll
        for (int i = 0; i < 4; ++i) {
            const int b = blk * 16 + l4 * 4 + i;
            const int j = j0 + jt * 16 + l15;
            float h = h0[b * 256 + j];
            hprev[jt][i] = h;
            *(unsigned short*)(hwp + i * 64 + jt * 32) = f2bf(h);
        }

    const char* xqb = xg + blk * 24576 + tid * 48;
    unsigned int ooff = (unsigned)((blk * 16 + l4 * 4) * (SEQ * 256) + j0 + l15) * 4u;

    uint4 xq0 = *(const uint4*)(xqb + 0);
    uint4 xq1 = *(const uint4*)(xqb + 16);
    uint4 xq2 = *(const uint4*)(xqb + 32);
    const char* xqn = xqb + SLAB;   // prefetch source (slab t+1)

    asm volatile("s_waitcnt lgkmcnt(0)" ::: "memory");
    __builtin_amdgcn_s_barrier();
    __builtin_amdgcn_sched_barrier(0);

#define GATES(P_, JT_, AR, AZ, AN, QX, QY) do { \
    float xn[4] = { bflo(QX), bfhi(QX), bflo(QY), bfhi(QY) }; \
    _Pragma("unroll") for (int i = 0; i < 4; ++i) { \
        float r   = __builtin_amdgcn_rcpf(1.0f + __builtin_amdgcn_exp2f(AR[i])); \
        float uu  = __builtin_amdgcn_rcpf(1.0f + __builtin_amdgcn_exp2f(AZ[i])); \
        float pre = fmaf(r, AN[i], xn[i]); \
        float nn  = fmaf(-2.0f, __builtin_amdgcn_rcpf(1.0f + __builtin_amdgcn_exp2f(pre)), 1.0f); \
        float hp  = hprev[JT_][i]; \
        float hnv = fmaf(uu, nn - hp, hp); \
        hprev[JT_][i] = hnv; \
        *(unsigned short*)(hwp + i * 64 + (JT_) * 32 + (1 - (P_)) * 8192) = f2bf(hnv); \
        *(float*)((char*)out + (ooff + (unsigned)i * (SEQ * 1024u) + (JT_) * 64u)) = hnv; \
    } } while (0)

#define BODY(T_, P_) do { \
    f32x4 acc0 = { bflo(xq0.x), bfhi(xq0.x), bflo(xq0.y), bfhi(xq0.y) }; \
    f32x4 acc1 = { bflo(xq0.z), bfhi(xq0.z), bflo(xq0.w), bfhi(xq0.w) }; \
    f32x4 acc2 = { bflo(xq1.x), bfhi(xq1.x), bflo(xq1.y), bfhi(xq1.y) }; \
    f32x4 acc3 = { bflo(xq1.z), bfhi(xq1.z), bflo(xq1.w), bfhi(xq1.w) }; \
    f32x4 acc4 = { bHn[0], bHn[0], bHn[0], bHn[0] }; \
    f32x4 acc5 = { bHn[1], bHn[1], bHn[1], bHn[1] }; \
    _Pragma("unroll") for (int kk = 0; kk < 8; ++kk) { \
        bf16x8 a_ = *(const bf16x8*)(hrp + (kk * 1024 + (P_) * 8192)); \
        acc0 = __builtin_amdgcn_mfma_f32_16x16x32_bf16(a_, wf[0][kk], acc0, 0, 0, 0); \
        acc1 = __builtin_amdgcn_mfma_f32_16x16x32_bf16(a_, wf[1][kk], acc1, 0, 0, 0); \
        acc2 = __builtin_amdgcn_mfma_f32_16x16x32_bf16(a_, wf[2][kk], acc2, 0, 0, 0); \
        acc3 = __builtin_amdgcn_mfma_f32_16x16x32_bf16(a_, wf[3][kk], acc3, 0, 0, 0); \
        acc4 = __builtin_amdgcn_mfma_f32_16x16x32_bf16(a_, wf[4][kk], acc4, 0, 0, 0); \
        acc5 = __builtin_amdgcn_mfma_f32_16x16x32_bf16(a_, wf[5][kk], acc5, 0, 0, 0); \
    } \
    xq0 = *(const uint4*)(xqn + 0); \
    xq1 = *(const uint4*)(xqn + 16); \
    GATES(P_, 0, acc0, acc2, acc4, xq2.x, xq2.y); \
    GATES(P_, 1, acc1, acc3, acc5, xq2.z, xq2.w); \
    xq2 = *(const uint4*)(xqn + 32); \
    if ((T_) + 2 < SEQ) xqn += SLAB; \
    ooff += 1024u; \
    asm volatile("s_waitcnt lgkmcnt(0)" ::: "memory"); \
    __builtin_amdgcn_s_barrier(); \
    __builtin_amdgcn_sched_barrier(0); \
} while (0)

    for (int tt = 0; tt < SEQ; tt += 2) {
        BODY(tt + 0, 0);
        BODY(tt + 1, 1);
    }
#undef BODY
#undef GATES
}

extern "C" void kernel_launch(void* const* d_in, const int* in_sizes, int n_in,
                              void* d_out, int out_size, void* d_ws, size_t ws_size,
                              hipStream_t stream) {
    const float* x    = (const float*)d_in[0];
    const float* h0   = (const float*)d_in[1];
    const float* w_ih = (const float*)d_in[2];
    const float* w_hh = (const float*)d_in[3];
    const float* b_ih = (const float*)d_in[4];
    const float* b_hh = (const float*)d_in[5];
    float* out = (float*)d_out;
    char* xg = (char*)d_ws;   // needs SEQ*49152 = 192 MB

    (void)in_sizes; (void)n_in; (void)out_size; (void)ws_size;

    gru_xproj<<<dim3(SEQ / 32, 2), dim3(512), 0, stream>>>(x, w_ih, b_ih, b_hh, xg);
    gru_rec<<<dim3(2), dim3(512), 0, stream>>>(w_hh, b_hh, h0, xg, out);
}